// Round 9
// baseline (531.734 us; speedup 1.0000x reference)
//
#include <hip/hip_runtime.h>

// Cvxpy_81174881894666: batched dual ascent (R9: v_pk_fma_f32 packed math)
//   per batch b: 100 iters of
//     z = a^T lam;  y = sigmoid(-(c+z));  g = a y + b;  lam = max(lam+0.05 g, 0)
//   out: y = sigmoid(-(c + a^T lam_final)) [2048,256] f32, status int32 zeros.
//
// R7/R8 post-mortem: VALU-issue-bound at 475us; measured VALU cycles = 2.1x
// source inst count; VGPR_Count=52 < pinned-tile size (AGPR shelving and/or
// packed-math-assumed f32 peak). R9: all 128 MAC/iter via v_pk_fma_f32
// inline asm (2 MAC/inst), A stored as 32 even-aligned register PAIRS
// (A[2r][c],A[2r+1][c]) - asm "v" constraints force arch-VGPR residency at
// every use. P1 lam pairs come straight from LDS (no broadcast); P3 pair
// outputs (p[2r],p[2r+1]) unpack into the verified reduce tree unchanged.

#define BB 2048
#define MM 128
#define NN 256
#define NITER 100
#define STEP_ 0.05f

typedef unsigned int u32;
typedef u32 u32x2 __attribute__((ext_vector_type(2)));
typedef float f2 __attribute__((ext_vector_type(2)));

__device__ __forceinline__ void plane32_swap(float& a, float& b) {
    u32x2 r = __builtin_amdgcn_permlane32_swap(__float_as_uint(a), __float_as_uint(b), false, false);
    a = __uint_as_float(r[0]);
    b = __uint_as_float(r[1]);
}
__device__ __forceinline__ void plane16_swap(float& a, float& b) {
    u32x2 r = __builtin_amdgcn_permlane16_swap(__float_as_uint(a), __float_as_uint(b), false, false);
    a = __uint_as_float(r[0]);
    b = __uint_as_float(r[1]);
}
// acc = a*b + acc, two f32 lanes per instruction
__device__ __forceinline__ void pkfma(f2& acc, f2 a, f2 b) {
    asm("v_pk_fma_f32 %0, %1, %2, %0" : "+v"(acc) : "v"(a), "v"(b));
}

__global__ __launch_bounds__(512, 2) void cvx_dual_ascent(
    const float* __restrict__ A,
    const float* __restrict__ Bv,
    const float* __restrict__ C,
    float* __restrict__ out)
{
    const int bi  = blockIdx.x;
    const int tid = threadIdx.x;
    const int w   = tid >> 6;        // wave 0..7 -> rows [16w, 16w+16)
    const int l   = tid & 63;        // lane
    const int colq = l * 4;          // my 4 columns (A and y)
    const int myrow = (l >> 2) & 15; // row I own after the reduce

    __shared__ float zp_s[8][260];   // z partials [wave][col]
    __shared__ float y_s[NN];
    __shared__ float lam_s[8][16];   // per-wave lambda (wave-private)

    // ---- load A row-pairs: apair[r][j] = (A[2r][colq+j], A[2r+1][colq+j]) ----
    const float* Ab = A + (size_t)bi * (MM * NN);
    f2 apair[8][4];
    #pragma unroll
    for (int r = 0; r < 8; ++r) {
        const float4 e = *reinterpret_cast<const float4*>(Ab + (w*16 + 2*r    ) * NN + colq);
        const float4 o = *reinterpret_cast<const float4*>(Ab + (w*16 + 2*r + 1) * NN + colq);
        apair[r][0] = f2{e.x, o.x};
        apair[r][1] = f2{e.y, o.y};
        apair[r][2] = f2{e.z, o.z};
        apair[r][3] = f2{e.w, o.w};
    }
    #pragma unroll
    for (int r = 0; r < 8; ++r)
        #pragma unroll
        for (int j = 0; j < 4; ++j)
            asm volatile("" : "+v"(apair[r][j]));   // pin pairs in arch VGPRs

    const float sb  = STEP_ * Bv[bi * MM + w * 16 + myrow];  // 0.05*b for my row
    const int   col = tid >> 1;       // P2: 2 threads per column
    const int   h   = tid & 1;
    const float c_r = C[bi * NN + col];
    float lam = 0.f;                  // lambda[my row], quad-replicated

    if (tid < 128) lam_s[tid >> 4][tid & 15] = 0.f;
    __syncthreads();

    for (int it = 0; it <= NITER; ++it) {
        // ---- P1: z partials, packed: acc[j] accumulates (even-rows, odd-rows) ----
        const float4 lv0 = *reinterpret_cast<const float4*>(&lam_s[w][0]);
        const float4 lv1 = *reinterpret_cast<const float4*>(&lam_s[w][4]);
        const float4 lv2 = *reinterpret_cast<const float4*>(&lam_s[w][8]);
        const float4 lv3 = *reinterpret_cast<const float4*>(&lam_s[w][12]);
        const f2 lp[8] = {f2{lv0.x, lv0.y}, f2{lv0.z, lv0.w},
                          f2{lv1.x, lv1.y}, f2{lv1.z, lv1.w},
                          f2{lv2.x, lv2.y}, f2{lv2.z, lv2.w},
                          f2{lv3.x, lv3.y}, f2{lv3.z, lv3.w}};
        f2 acc0 = f2{0.f, 0.f}, acc1 = f2{0.f, 0.f};
        f2 acc2 = f2{0.f, 0.f}, acc3 = f2{0.f, 0.f};
        #pragma unroll
        for (int r = 0; r < 8; ++r) {
            pkfma(acc0, apair[r][0], lp[r]);
            pkfma(acc1, apair[r][1], lp[r]);
            pkfma(acc2, apair[r][2], lp[r]);
            pkfma(acc3, apair[r][3], lp[r]);
        }
        *reinterpret_cast<float4*>(&zp_s[w][colq]) =
            make_float4(acc0.x + acc0.y, acc1.x + acc1.y,
                        acc2.x + acc2.y, acc3.x + acc3.y);
        __syncthreads();  // B1

        // ---- P2: z = sum over 8 waves; 2 threads per column ----
        float z = zp_s[h * 4 + 0][col] + zp_s[h * 4 + 1][col]
                + zp_s[h * 4 + 2][col] + zp_s[h * 4 + 3][col];
        z += __shfl_xor(z, 1);
        const float e = __expf(c_r + z);                    // v_exp-based
        const float y = __builtin_amdgcn_rcpf(1.0f + e);    // sigmoid(-(c+z))

        if (it == NITER) {                                  // uniform exit
            if (h == 0) out[(size_t)bi * NN + col] = y;
            break;
        }
        if (h == 0) y_s[col] = y;
        __syncthreads();  // B2

        // ---- P3: packed g: pr[r] = (p[2r], p[2r+1]) ----
        const float4 y4 = *reinterpret_cast<const float4*>(&y_s[colq]);
        const f2 yb0 = f2{y4.x, y4.x}, yb1 = f2{y4.y, y4.y};
        const f2 yb2 = f2{y4.z, y4.z}, yb3 = f2{y4.w, y4.w};
        f2 pr[8];
        #pragma unroll
        for (int r = 0; r < 8; ++r) {
            f2 a0 = f2{0.f, 0.f};
            pkfma(a0, apair[r][0], yb0);
            pkfma(a0, apair[r][1], yb1);
            pkfma(a0, apair[r][2], yb2);
            pkfma(a0, apair[r][3], yb3);
            pr[r] = a0;
        }
        float p[16];
        #pragma unroll
        for (int r = 0; r < 8; ++r) { p[2*r] = pr[r].x; p[2*r + 1] = pr[r].y; }

        // Round 1 (lane-pair l,l^32): permlane32_swap + add.
        float q[8];
        #pragma unroll
        for (int k = 0; k < 8; ++k) {
            float a0 = p[k], b0 = p[k + 8];
            plane32_swap(a0, b0);
            q[k] = a0 + b0;
        }
        // Round 2 (l,l^16): permlane16_swap + add.
        float r2[4];
        #pragma unroll
        for (int k = 0; k < 4; ++k) {
            float a0 = q[k], b0 = q[k + 4];
            plane16_swap(a0, b0);
            r2[k] = a0 + b0;
        }
        // Round 3 (mask 8, scrambled): bit3 -> rows +2.
        const bool b3 = (l & 8) != 0;
        float s0, s1;
        {
            const float k0 = b3 ? r2[2] : r2[0];
            const float d0 = b3 ? r2[0] : r2[2];
            s0 = k0 + __shfl_xor(d0, 8);
            const float k1 = b3 ? r2[3] : r2[1];
            const float d1 = b3 ? r2[1] : r2[3];
            s1 = k1 + __shfl_xor(d1, 8);
        }
        // Round 4 (mask 4, scrambled): bit2 -> rows +1. Then replicate quads.
        const bool b2 = (l & 4) != 0;
        {
            const float keep = b2 ? s1 : s0;
            const float send = b2 ? s0 : s1;
            float g = keep + __shfl_xor(send, 4);
            g += __shfl_xor(g, 2);
            g += __shfl_xor(g, 1);
            lam = fmaxf(fmaf(STEP_, g, lam) + sb, 0.f);
        }
        if ((l & 3) == 0) lam_s[w][myrow] = lam;   // in-wave publish
        // no barrier: lam_s[w] read only by wave w (in-wave DS order)
    }

    if (tid == 0) out[(size_t)BB * NN + bi] = 0.0f;  // status[bi] = int32 0
}

extern "C" void kernel_launch(void* const* d_in, const int* in_sizes, int n_in,
                              void* d_out, int out_size, void* d_ws, size_t ws_size,
                              hipStream_t stream) {
    const float* A  = (const float*)d_in[0];  // [2048,128,256]
    const float* Bv = (const float*)d_in[1];  // [2048,128]
    const float* C  = (const float*)d_in[2];  // [2048,256]
    float* out = (float*)d_out;               // y [2048,256] f32 ++ status [2048]

    cvx_dual_ascent<<<dim3(BB), dim3(512), 0, stream>>>(A, Bv, C, out);
}

// Round 10
// 528.993 us; speedup vs baseline: 1.0052x; 1.0052x over previous
//
#include <hip/hip_runtime.h>

// Cvxpy_81174881894666: batched dual ascent (R10: defeat AGPR shelving)
//   per batch b: 100 iters of
//     z = a^T lam;  y = sigmoid(-(c+z));  g = a y + b;  lam = max(lam+0.05 g, 0)
//   out: y = sigmoid(-(c + a^T lam_final)) [2048,256] f32, status int32 zeros.
//
// R9 post-mortem: v_pk_fma_f32 is NOT double-rate on CDNA4 (157.3 TF = scalar
// v_fma at 1/lane/cy) -> reverted to R8 scalar structure (475us).
// Persistent issue: VGPR_Count=52-56 < 64 A-floats -> tile homed in AGPRs,
// ~128 v_accvgpr_read/iter (measured 313 inst-equiv/iter vs 185 in source).
// R10 anchors the tile in arch VGPRs:
//   1) amdgpu_waves_per_eu(2,4): max 4 waves/EU -> allocator budget floor
//      512/4=128 regs -> shelving buys no occupancy, no incentive.
//   2) re-pin all 64 A-components at the TOP OF EVERY ITERATION: AGPR home
//      would now cost 64 copies/iter vs 0 for VGPR home.

#define BB 2048
#define MM 128
#define NN 256
#define NITER 100
#define STEP_ 0.05f

typedef unsigned int u32;
typedef u32 u32x2 __attribute__((ext_vector_type(2)));

__device__ __forceinline__ void plane32_swap(float& a, float& b) {
    u32x2 r = __builtin_amdgcn_permlane32_swap(__float_as_uint(a), __float_as_uint(b), false, false);
    a = __uint_as_float(r[0]);
    b = __uint_as_float(r[1]);
}
__device__ __forceinline__ void plane16_swap(float& a, float& b) {
    u32x2 r = __builtin_amdgcn_permlane16_swap(__float_as_uint(a), __float_as_uint(b), false, false);
    a = __uint_as_float(r[0]);
    b = __uint_as_float(r[1]);
}

__global__ __attribute__((amdgpu_flat_work_group_size(512, 512),
                          amdgpu_waves_per_eu(2, 4)))
void cvx_dual_ascent(
    const float* __restrict__ A,
    const float* __restrict__ Bv,
    const float* __restrict__ C,
    float* __restrict__ out)
{
    const int bi  = blockIdx.x;
    const int tid = threadIdx.x;
    const int w   = tid >> 6;        // wave 0..7 -> rows [16w, 16w+16)
    const int l   = tid & 63;        // lane
    const int colq = l * 4;          // my 4 columns (A and y)
    const int myrow = (l >> 2) & 15; // row I own after the reduce

    __shared__ float zp_s[8][260];   // z partials [wave][col]
    __shared__ float y_s[NN];
    __shared__ float lam_s[8][16];   // per-wave lambda (wave-private)

    // ---- load my 16 row-slices of A (read once), pin in regs ----
    const float* Ab = A + (size_t)bi * (MM * NN);
    float4 areg[16];
    #pragma unroll
    for (int i = 0; i < 16; ++i)
        areg[i] = *reinterpret_cast<const float4*>(Ab + (w * 16 + i) * NN + colq);
    #pragma unroll
    for (int i = 0; i < 16; ++i)
        asm volatile("" : "+v"(areg[i].x), "+v"(areg[i].y),
                          "+v"(areg[i].z), "+v"(areg[i].w));

    const float sb  = STEP_ * Bv[bi * MM + w * 16 + myrow];  // 0.05*b for my row
    const int   col = tid >> 1;       // P2: 2 threads per column
    const int   h   = tid & 1;
    const float c_r = C[bi * NN + col];
    float lam = 0.f;                  // lambda[my row], quad-replicated

    if (tid < 128) lam_s[tid >> 4][tid & 15] = 0.f;
    __syncthreads();

    for (int it = 0; it <= NITER; ++it) {
        // Per-iteration pin: anchors the A tile in arch VGPRs (an AGPR home
        // would now cost 64 copies/iter, so the allocator keeps VGPR home).
        #pragma unroll
        for (int i = 0; i < 16; ++i)
            asm volatile("" : "+v"(areg[i].x), "+v"(areg[i].y),
                              "+v"(areg[i].z), "+v"(areg[i].w));

        // ---- P1: z partials for my 4 cols over my wave's 16 rows ----
        const float4 lv0 = *reinterpret_cast<const float4*>(&lam_s[w][0]);
        const float4 lv1 = *reinterpret_cast<const float4*>(&lam_s[w][4]);
        const float4 lv2 = *reinterpret_cast<const float4*>(&lam_s[w][8]);
        const float4 lv3 = *reinterpret_cast<const float4*>(&lam_s[w][12]);
        const float lamv[16] = {lv0.x, lv0.y, lv0.z, lv0.w,
                                lv1.x, lv1.y, lv1.z, lv1.w,
                                lv2.x, lv2.y, lv2.z, lv2.w,
                                lv3.x, lv3.y, lv3.z, lv3.w};
        float4 zp = make_float4(0.f, 0.f, 0.f, 0.f);
        #pragma unroll
        for (int i = 0; i < 16; ++i) {
            zp.x = fmaf(areg[i].x, lamv[i], zp.x);
            zp.y = fmaf(areg[i].y, lamv[i], zp.y);
            zp.z = fmaf(areg[i].z, lamv[i], zp.z);
            zp.w = fmaf(areg[i].w, lamv[i], zp.w);
        }
        *reinterpret_cast<float4*>(&zp_s[w][colq]) = zp;
        __syncthreads();  // B1

        // ---- P2: z = sum over 8 waves; 2 threads per column ----
        float z = zp_s[h * 4 + 0][col] + zp_s[h * 4 + 1][col]
                + zp_s[h * 4 + 2][col] + zp_s[h * 4 + 3][col];
        z += __shfl_xor(z, 1);
        const float e = __expf(c_r + z);                    // v_exp-based
        const float y = __builtin_amdgcn_rcpf(1.0f + e);    // sigmoid(-(c+z))

        if (it == NITER) {                                  // uniform exit
            if (h == 0) out[(size_t)bi * NN + col] = y;
            break;
        }
        if (h == 0) y_s[col] = y;
        __syncthreads();  // B2

        // ---- P3: g for my wave's 16 rows (wave-local) ----
        const float4 y4 = *reinterpret_cast<const float4*>(&y_s[colq]);
        float p[16];
        #pragma unroll
        for (int k = 0; k < 16; ++k) {
            float acc =      areg[k].x * y4.x;
            acc = fmaf(areg[k].y, y4.y, acc);
            acc = fmaf(areg[k].z, y4.z, acc);
            p[k] = fmaf(areg[k].w, y4.w, acc);
        }
        // Round 1 (lane-pair l,l^32): permlane32_swap + add.
        float q[8];
        #pragma unroll
        for (int k = 0; k < 8; ++k) {
            float a0 = p[k], b0 = p[k + 8];
            plane32_swap(a0, b0);
            q[k] = a0 + b0;
        }
        // Round 2 (l,l^16): permlane16_swap + add.
        float r2[4];
        #pragma unroll
        for (int k = 0; k < 4; ++k) {
            float a0 = q[k], b0 = q[k + 4];
            plane16_swap(a0, b0);
            r2[k] = a0 + b0;
        }
        // Round 3 (mask 8, scrambled): bit3 -> rows +2.
        const bool b3 = (l & 8) != 0;
        float s0, s1;
        {
            const float k0 = b3 ? r2[2] : r2[0];
            const float d0 = b3 ? r2[0] : r2[2];
            s0 = k0 + __shfl_xor(d0, 8);
            const float k1 = b3 ? r2[3] : r2[1];
            const float d1 = b3 ? r2[1] : r2[3];
            s1 = k1 + __shfl_xor(d1, 8);
        }
        // Round 4 (mask 4, scrambled): bit2 -> rows +1. Then replicate quads.
        const bool b2 = (l & 4) != 0;
        {
            const float keep = b2 ? s1 : s0;
            const float send = b2 ? s0 : s1;
            float g = keep + __shfl_xor(send, 4);
            g += __shfl_xor(g, 2);
            g += __shfl_xor(g, 1);
            lam = fmaxf(fmaf(STEP_, g, lam) + sb, 0.f);
        }
        if ((l & 3) == 0) lam_s[w][myrow] = lam;   // in-wave publish
        // no barrier: lam_s[w] read only by wave w (in-wave DS order)
    }

    if (tid == 0) out[(size_t)BB * NN + bi] = 0.0f;  // status[bi] = int32 0
}

extern "C" void kernel_launch(void* const* d_in, const int* in_sizes, int n_in,
                              void* d_out, int out_size, void* d_ws, size_t ws_size,
                              hipStream_t stream) {
    const float* A  = (const float*)d_in[0];  // [2048,128,256]
    const float* Bv = (const float*)d_in[1];  // [2048,128]
    const float* C  = (const float*)d_in[2];  // [2048,256]
    float* out = (float*)d_out;               // y [2048,256] f32 ++ status [2048]

    cvx_dual_ascent<<<dim3(BB), dim3(512), 0, stream>>>(A, Bv, C, out);
}

// Round 11
// 453.794 us; speedup vs baseline: 1.1718x; 1.1657x over previous
//
#include <hip/hip_runtime.h>

// Cvxpy_81174881894666: batched dual ascent (R11: critical-path shortening)
//   per batch b: 100 iters of
//     z = a^T lam;  y = sigmoid(-(c+z));  g = a y + b;  lam = max(lam+0.05 g, 0)
//   out: y = sigmoid(-(c + a^T lam_final)) [2048,256] f32, status int32 zeros.
//
// R10 post-mortem: allocator won't un-shelve the A tile (VGPR 56, 529us);
// per-iter pins added copies. Model re-audit: gfx94x-formula VALUBusy is
// likely 2x-inflated on gfx950 (SIMD-32 vs SIMD-16) -> true ~45%, kernel is
// LATENCY/BARRIER-bound. Evidence: R6->R7 saved 2.7x the pure-issue value
// (ops were on the serial path); R9's added ops cost less than issue-model
// (off-path, hidden). R11 shortens the serial path, structure unchanged:
//  - P1 FMA chain split into 2x8 rows (dep chain 64 -> ~36 cy)
//  - mask-1/2 shuffles -> DPP quad_perm adds (VALU dep ~4cy vs swizzle ~25)
//  - mask-8 exchanges -> DPP row_ror:8 (== xor8 within 16-lane rows)

#define BB 2048
#define MM 128
#define NN 256
#define NITER 100
#define STEP_ 0.05f

typedef unsigned int u32;
typedef u32 u32x2 __attribute__((ext_vector_type(2)));

__device__ __forceinline__ void plane32_swap(float& a, float& b) {
    u32x2 r = __builtin_amdgcn_permlane32_swap(__float_as_uint(a), __float_as_uint(b), false, false);
    a = __uint_as_float(r[0]);
    b = __uint_as_float(r[1]);
}
__device__ __forceinline__ void plane16_swap(float& a, float& b) {
    u32x2 r = __builtin_amdgcn_permlane16_swap(__float_as_uint(a), __float_as_uint(b), false, false);
    a = __uint_as_float(r[0]);
    b = __uint_as_float(r[1]);
}
// x_from_lane(l^1): DPP quad_perm [1,0,3,2] = 0xB1
__device__ __forceinline__ float dpp_xor1(float x) {
    return __int_as_float(__builtin_amdgcn_update_dpp(
        0, __float_as_int(x), 0xB1, 0xF, 0xF, true));
}
// x_from_lane(l^2): DPP quad_perm [2,3,0,1] = 0x4E
__device__ __forceinline__ float dpp_xor2(float x) {
    return __int_as_float(__builtin_amdgcn_update_dpp(
        0, __float_as_int(x), 0x4E, 0xF, 0xF, true));
}
// x_from_lane(l^8): DPP row_ror:8 = 0x128 (== xor8 within each 16-lane row)
__device__ __forceinline__ float dpp_xor8(float x) {
    return __int_as_float(__builtin_amdgcn_update_dpp(
        0, __float_as_int(x), 0x128, 0xF, 0xF, true));
}

__global__ __launch_bounds__(512, 2) void cvx_dual_ascent(
    const float* __restrict__ A,
    const float* __restrict__ Bv,
    const float* __restrict__ C,
    float* __restrict__ out)
{
    const int bi  = blockIdx.x;
    const int tid = threadIdx.x;
    const int w   = tid >> 6;        // wave 0..7 -> rows [16w, 16w+16)
    const int l   = tid & 63;        // lane
    const int colq = l * 4;          // my 4 columns (A and y)
    const int myrow = (l >> 2) & 15; // row I own after the reduce

    __shared__ float zp_s[8][260];   // z partials [wave][col]
    __shared__ float y_s[NN];
    __shared__ float lam_s[8][16];   // per-wave lambda (wave-private)

    // ---- load my 16 row-slices of A (read once), pin in regs ----
    const float* Ab = A + (size_t)bi * (MM * NN);
    float4 areg[16];
    #pragma unroll
    for (int i = 0; i < 16; ++i)
        areg[i] = *reinterpret_cast<const float4*>(Ab + (w * 16 + i) * NN + colq);
    #pragma unroll
    for (int i = 0; i < 16; ++i)
        asm volatile("" : "+v"(areg[i].x), "+v"(areg[i].y),
                          "+v"(areg[i].z), "+v"(areg[i].w));

    const float sb  = STEP_ * Bv[bi * MM + w * 16 + myrow];  // 0.05*b for my row
    const int   col = tid >> 1;       // P2: 2 threads per column
    const int   h   = tid & 1;
    const float c_r = C[bi * NN + col];
    float lam = 0.f;                  // lambda[my row], quad-replicated

    if (tid < 128) lam_s[tid >> 4][tid & 15] = 0.f;
    __syncthreads();

    for (int it = 0; it <= NITER; ++it) {
        // ---- P1: z partials; 2x8-row accumulator split (short dep chain) ----
        const float4 lv0 = *reinterpret_cast<const float4*>(&lam_s[w][0]);
        const float4 lv1 = *reinterpret_cast<const float4*>(&lam_s[w][4]);
        const float4 lv2 = *reinterpret_cast<const float4*>(&lam_s[w][8]);
        const float4 lv3 = *reinterpret_cast<const float4*>(&lam_s[w][12]);
        const float lamv[16] = {lv0.x, lv0.y, lv0.z, lv0.w,
                                lv1.x, lv1.y, lv1.z, lv1.w,
                                lv2.x, lv2.y, lv2.z, lv2.w,
                                lv3.x, lv3.y, lv3.z, lv3.w};
        float4 zpA = make_float4(0.f, 0.f, 0.f, 0.f);
        float4 zpB = make_float4(0.f, 0.f, 0.f, 0.f);
        #pragma unroll
        for (int i = 0; i < 8; ++i) {
            zpA.x = fmaf(areg[i].x, lamv[i], zpA.x);
            zpA.y = fmaf(areg[i].y, lamv[i], zpA.y);
            zpA.z = fmaf(areg[i].z, lamv[i], zpA.z);
            zpA.w = fmaf(areg[i].w, lamv[i], zpA.w);
            zpB.x = fmaf(areg[i + 8].x, lamv[i + 8], zpB.x);
            zpB.y = fmaf(areg[i + 8].y, lamv[i + 8], zpB.y);
            zpB.z = fmaf(areg[i + 8].z, lamv[i + 8], zpB.z);
            zpB.w = fmaf(areg[i + 8].w, lamv[i + 8], zpB.w);
        }
        *reinterpret_cast<float4*>(&zp_s[w][colq]) =
            make_float4(zpA.x + zpB.x, zpA.y + zpB.y,
                        zpA.z + zpB.z, zpA.w + zpB.w);
        __syncthreads();  // B1

        // ---- P2: z = sum over 8 waves; 2 threads per column ----
        float z = zp_s[h * 4 + 0][col] + zp_s[h * 4 + 1][col]
                + zp_s[h * 4 + 2][col] + zp_s[h * 4 + 3][col];
        z += dpp_xor1(z);                                   // pair-sum (l ^ 1)
        const float e = __expf(c_r + z);                    // v_exp-based
        const float y = __builtin_amdgcn_rcpf(1.0f + e);    // sigmoid(-(c+z))

        if (it == NITER) {                                  // uniform exit
            if (h == 0) out[(size_t)bi * NN + col] = y;
            break;
        }
        if (h == 0) y_s[col] = y;
        __syncthreads();  // B2

        // ---- P3: g for my wave's 16 rows (wave-local) ----
        const float4 y4 = *reinterpret_cast<const float4*>(&y_s[colq]);
        float p[16];
        #pragma unroll
        for (int k = 0; k < 16; ++k) {
            float acc =      areg[k].x * y4.x;
            acc = fmaf(areg[k].y, y4.y, acc);
            acc = fmaf(areg[k].z, y4.z, acc);
            p[k] = fmaf(areg[k].w, y4.w, acc);
        }
        // Round 1 (lane-pair l,l^32): permlane32_swap + add.
        float q[8];
        #pragma unroll
        for (int k = 0; k < 8; ++k) {
            float a0 = p[k], b0 = p[k + 8];
            plane32_swap(a0, b0);
            q[k] = a0 + b0;
        }
        // Round 2 (l,l^16): permlane16_swap + add.
        float r2[4];
        #pragma unroll
        for (int k = 0; k < 4; ++k) {
            float a0 = q[k], b0 = q[k + 4];
            plane16_swap(a0, b0);
            r2[k] = a0 + b0;
        }
        // Round 3 (mask 8, scrambled) via DPP row_ror:8 (== xor8 in-row).
        const bool b3 = (l & 8) != 0;
        float s0, s1;
        {
            const float k0 = b3 ? r2[2] : r2[0];
            const float d0 = b3 ? r2[0] : r2[2];
            s0 = k0 + dpp_xor8(d0);
            const float k1 = b3 ? r2[3] : r2[1];
            const float d1 = b3 ? r2[1] : r2[3];
            s1 = k1 + dpp_xor8(d1);
        }
        // Round 4 (mask 4, scrambled, ds_swizzle) then DPP butterflies 2,1.
        const bool b2 = (l & 4) != 0;
        {
            const float keep = b2 ? s1 : s0;
            const float send = b2 ? s0 : s1;
            float g = keep + __shfl_xor(send, 4);
            g += dpp_xor2(g);
            g += dpp_xor1(g);
            lam = fmaxf(fmaf(STEP_, g, lam) + sb, 0.f);
        }
        if ((l & 3) == 0) lam_s[w][myrow] = lam;   // in-wave publish
        // no barrier: lam_s[w] read only by wave w (in-wave DS order)
    }

    if (tid == 0) out[(size_t)BB * NN + bi] = 0.0f;  // status[bi] = int32 0
}

extern "C" void kernel_launch(void* const* d_in, const int* in_sizes, int n_in,
                              void* d_out, int out_size, void* d_ws, size_t ws_size,
                              hipStream_t stream) {
    const float* A  = (const float*)d_in[0];  // [2048,128,256]
    const float* Bv = (const float*)d_in[1];  // [2048,128]
    const float* C  = (const float*)d_in[2];  // [2048,256]
    float* out = (float*)d_out;               // y [2048,256] f32 ++ status [2048]

    cvx_dual_ascent<<<dim3(BB), dim3(512), 0, stream>>>(A, Bv, C, out);
}